// Round 15
// baseline (696.868 us; speedup 1.0000x reference)
//
#include <hip/hip_runtime.h>
#include <math.h>

// Problem constants
constexpr int B_ = 8, S_ = 32, D_ = 256, M_ = 2048;
constexpr int N_ = S_ * B_;          // 256 (t,b) pairs, n = t*B + b
constexpr int TK = 8;                // TOPK
constexpr int NSLOT = 256;           // max distinct touched rows (8*31=248)
constexpr int TOPC = 256;            // precomputed top-C of L0 per (t,b)
constexpr int NCAND = NSLOT + TOPC;  // 512
constexpr int KSPLIT = 4;            // ctxpart split-K
constexpr int CACHE0 = 192;          // WvWgB rows [CACHE0,256) cached in LDS (64KB)

// ---------------------------------------------------------------------------
// K0: blocks 0..15: WvWgB[i][d] = sum_j Wv[i][j]*Wg[D+j][d]
//     block 16:     bvg[d] = bg[d] + sum_j bv[j]*Wg[D+j][d]
//     blocks 17..80: WkT[j][i] = Wk[i][j]
// ---------------------------------------------------------------------------
__global__ __launch_bounds__(256) void k_wvwgT(const float* __restrict__ Wv,
                                               const float* __restrict__ Wg,
                                               const float* __restrict__ bv,
                                               const float* __restrict__ bg,
                                               const float* __restrict__ Wk,
                                               float* __restrict__ WvWgB,
                                               float* __restrict__ bvg,
                                               float* __restrict__ WkT) {
  int blk = blockIdx.x;
  int tid = threadIdx.x;
  if (blk >= 17) {
    __shared__ float tile[32][33];
    int bb = blk - 17;
    int bx = bb & 7, by = bb >> 3;
    int x0 = bx * 32, y0 = by * 32;
    int tx = tid & 31, ty = tid >> 5;
    for (int j = ty; j < 32; j += 8) tile[j][tx] = Wk[(y0 + j) * D_ + x0 + tx];
    __syncthreads();
    for (int j = ty; j < 32; j += 8) WkT[(x0 + j) * D_ + y0 + tx] = tile[tx][j];
    return;
  }
  if (blk == 16) {
    float a = bg[tid];
#pragma unroll 8
    for (int j = 0; j < D_; ++j) a = fmaf(bv[j], Wg[(size_t)(D_ + j) * D_ + tid], a);
    bvg[tid] = a;
    return;
  }
  int i0 = (blk & 3) * 64, d0 = (blk >> 2) * 64;
  __shared__ float At[64 * 64];  // [j][i]
  __shared__ float Bt[64 * 64];  // [j][d]
  const int r = tid & 63, c = tid >> 6;
  const int lane = tid & 63, wvv = tid >> 6;
  const int tx = lane & 15, ty = lane >> 4;
  const int dg = tx * 4, ig = (wvv * 4 + ty) * 4;
  float acc[4][4];
#pragma unroll
  for (int i = 0; i < 4; ++i)
#pragma unroll
    for (int j = 0; j < 4; ++j) acc[i][j] = 0.f;
  for (int kc = 0; kc < 4; ++kc) {
    __syncthreads();
#pragma unroll
    for (int it = 0; it < 4; ++it) {
      int jq = (c * 4 + it) * 4;
      float4 a = *(const float4*)&Wv[(i0 + r) * D_ + kc * 64 + jq];
      At[(jq + 0) * 64 + r] = a.x; At[(jq + 1) * 64 + r] = a.y;
      At[(jq + 2) * 64 + r] = a.z; At[(jq + 3) * 64 + r] = a.w;
      *(float4*)&Bt[r * 64 + jq] =
          *(const float4*)&Wg[(size_t)(D_ + kc * 64 + r) * D_ + d0 + jq];
    }
    __syncthreads();
#pragma unroll 4
    for (int j = 0; j < 64; ++j) {
      float4 av = *(const float4*)&At[j * 64 + ig];
      float4 bv4 = *(const float4*)&Bt[j * 64 + dg];
      acc[0][0] = fmaf(av.x, bv4.x, acc[0][0]); acc[0][1] = fmaf(av.x, bv4.y, acc[0][1]);
      acc[0][2] = fmaf(av.x, bv4.z, acc[0][2]); acc[0][3] = fmaf(av.x, bv4.w, acc[0][3]);
      acc[1][0] = fmaf(av.y, bv4.x, acc[1][0]); acc[1][1] = fmaf(av.y, bv4.y, acc[1][1]);
      acc[1][2] = fmaf(av.y, bv4.z, acc[1][2]); acc[1][3] = fmaf(av.y, bv4.w, acc[1][3]);
      acc[2][0] = fmaf(av.z, bv4.x, acc[2][0]); acc[2][1] = fmaf(av.z, bv4.y, acc[2][1]);
      acc[2][2] = fmaf(av.z, bv4.z, acc[2][2]); acc[2][3] = fmaf(av.z, bv4.w, acc[2][3]);
      acc[3][0] = fmaf(av.w, bv4.x, acc[3][0]); acc[3][1] = fmaf(av.w, bv4.y, acc[3][1]);
      acc[3][2] = fmaf(av.w, bv4.z, acc[3][2]); acc[3][3] = fmaf(av.w, bv4.w, acc[3][3]);
    }
  }
#pragma unroll
  for (int i = 0; i < 4; ++i)
    *(float4*)&WvWgB[(size_t)(i0 + ig + i) * D_ + d0 + dg] =
        make_float4(acc[i][0], acc[i][1], acc[i][2], acc[i][3]);
}

// ---------------------------------------------------------------------------
// K1: per n=(t,b): q = xt@Wq+bq ; qt[d]=sum_i q[i]*WkT[i][d] ; qbk = q.bk ;
//     xgpre = xt @ Wg[0:D,:]
// ---------------------------------------------------------------------------
__global__ __launch_bounds__(256) void k_qproj(
    const float* __restrict__ x, const float* __restrict__ Wq,
    const float* __restrict__ bq, const float* __restrict__ bk,
    const float* __restrict__ WkT, const float* __restrict__ Wg,
    float* __restrict__ qt, float* __restrict__ qbk, float* __restrict__ xgp) {
  int n = blockIdx.x, tid = threadIdx.x;
  int t = n / B_, b = n % B_;
  __shared__ float xr[D_], qsh[D_];
  __shared__ float red[4];
  xr[tid] = x[(b * S_ + t) * D_ + tid];
  __syncthreads();
  float accq = bq[tid], accg = 0.f;
#pragma unroll 8
  for (int i = 0; i < D_; ++i) {
    float xv = xr[i];
    accq = fmaf(xv, Wq[i * D_ + tid], accq);
    accg = fmaf(xv, Wg[i * D_ + tid], accg);
  }
  qsh[tid] = accq;
  xgp[n * D_ + tid] = accg;
  float p = accq * bk[tid];
  for (int off = 32; off > 0; off >>= 1) p += __shfl_down(p, off, 64);
  if ((tid & 63) == 0) red[tid >> 6] = p;
  __syncthreads();
  float acct = 0.f;
#pragma unroll 8
  for (int i = 0; i < D_; ++i) acct = fmaf(qsh[i], WkT[i * D_ + tid], acct);
  qt[n * D_ + tid] = acct;
  if (tid == 0) qbk[n] = red[0] + red[1] + red[2] + red[3];
}

// ---------------------------------------------------------------------------
// K2: L0[n][m] = (memory[m] . qt[n] + qbk[n]) / 16
// ---------------------------------------------------------------------------
__global__ __launch_bounds__(256) void k_L0(
    const float* __restrict__ qt, const float* __restrict__ mem,
    const float* __restrict__ qbk, float* __restrict__ L0) {
  __shared__ float qtT[64 * 64];
  __shared__ float mT[64 * 64];
  const int tid = threadIdx.x;
  const int m0 = blockIdx.x * 64, n0 = blockIdx.y * 64;
  const int r = tid & 63, c = tid >> 6;
  const int lane = tid & 63, wv = tid >> 6;
  const int tx = lane & 15, ty = lane >> 4;
  const int mg = tx * 4, ng = (wv * 4 + ty) * 4;
  float acc[4][4];
#pragma unroll
  for (int i = 0; i < 4; ++i)
#pragma unroll
    for (int j = 0; j < 4; ++j) acc[i][j] = 0.f;
  for (int kc = 0; kc < 4; ++kc) {
    __syncthreads();
#pragma unroll
    for (int it = 0; it < 4; ++it) {
      int kq = (c * 4 + it) * 4;
      float4 a = *(const float4*)&qt[(n0 + r) * D_ + kc * 64 + kq];
      qtT[(kq + 0) * 64 + r] = a.x; qtT[(kq + 1) * 64 + r] = a.y;
      qtT[(kq + 2) * 64 + r] = a.z; qtT[(kq + 3) * 64 + r] = a.w;
      float4 bm = *(const float4*)&mem[(m0 + r) * D_ + kc * 64 + kq];
      mT[(kq + 0) * 64 + r] = bm.x; mT[(kq + 1) * 64 + r] = bm.y;
      mT[(kq + 2) * 64 + r] = bm.z; mT[(kq + 3) * 64 + r] = bm.w;
    }
    __syncthreads();
#pragma unroll 4
    for (int k = 0; k < 64; ++k) {
      float4 av = *(const float4*)&qtT[k * 64 + ng];
      float4 bv4 = *(const float4*)&mT[k * 64 + mg];
      acc[0][0] = fmaf(av.x, bv4.x, acc[0][0]); acc[0][1] = fmaf(av.x, bv4.y, acc[0][1]);
      acc[0][2] = fmaf(av.x, bv4.z, acc[0][2]); acc[0][3] = fmaf(av.x, bv4.w, acc[0][3]);
      acc[1][0] = fmaf(av.y, bv4.x, acc[1][0]); acc[1][1] = fmaf(av.y, bv4.y, acc[1][1]);
      acc[1][2] = fmaf(av.y, bv4.z, acc[1][2]); acc[1][3] = fmaf(av.y, bv4.w, acc[1][3]);
      acc[2][0] = fmaf(av.z, bv4.x, acc[2][0]); acc[2][1] = fmaf(av.z, bv4.y, acc[2][1]);
      acc[2][2] = fmaf(av.z, bv4.z, acc[2][2]); acc[2][3] = fmaf(av.z, bv4.w, acc[2][3]);
      acc[3][0] = fmaf(av.w, bv4.x, acc[3][0]); acc[3][1] = fmaf(av.w, bv4.y, acc[3][1]);
      acc[3][2] = fmaf(av.w, bv4.z, acc[3][2]); acc[3][3] = fmaf(av.w, bv4.w, acc[3][3]);
    }
  }
#pragma unroll
  for (int i = 0; i < 4; ++i) {
    int n = n0 + ng + i;
    float qbv = qbk[n];
    float4 o;
    o.x = (acc[i][0] + qbv) * 0.0625f; o.y = (acc[i][1] + qbv) * 0.0625f;
    o.z = (acc[i][2] + qbv) * 0.0625f; o.w = (acc[i][3] + qbv) * 0.0625f;
    *(float4*)&L0[n * M_ + m0 + mg] = o;
  }
}

// ---------------------------------------------------------------------------
// K3: fused full bitonic sort (desc, tie idx asc) + top-256 + M0 + SumE0(fp64)
// 1024 threads: one compare-exchange per thread per stage (M_/2 = 1024).
// ---------------------------------------------------------------------------
__global__ __launch_bounds__(1024) void k_sortstats(const float* __restrict__ L0,
                                                    float* __restrict__ topv,
                                                    int* __restrict__ topi,
                                                    float* __restrict__ M0,
                                                    double* __restrict__ SumE0) {
  int n = blockIdx.x, tid = threadIdx.x;
  __shared__ float v[M_];
  __shared__ short ix[M_];
  __shared__ double redd[16];
  for (int m = tid; m < M_; m += 1024) {
    v[m] = L0[(size_t)n * M_ + m];
    ix[m] = (short)m;
  }
  __syncthreads();
  for (int size = 2; size <= M_; size <<= 1) {
    for (int stride = size >> 1; stride > 0; stride >>= 1) {
      const int i = tid;  // exactly M_/2 pairs
      const int pos = 2 * i - (i & (stride - 1));
      const int j = pos + stride;
      const bool desc = ((pos & size) == 0);
      const float va = v[pos], vb2 = v[j];
      const short ia = ix[pos], ib = ix[j];
      const bool aG = (va > vb2) || (va == vb2 && ia < ib);
      if (desc ? !aG : aG) { v[pos] = vb2; v[j] = va; ix[pos] = ib; ix[j] = ia; }
      __syncthreads();
    }
  }
  if (tid < TOPC) {
    topv[n * TOPC + tid] = v[tid];
    topi[n * TOPC + tid] = (int)ix[tid];
  }
  float mx = v[0];
  if (tid == 0) M0[n] = mx;
  double s = 0.0;
  for (int m = tid; m < M_; m += 1024) s += (double)expf(v[m] - mx);
  for (int off = 32; off > 0; off >>= 1) s += __shfl_down(s, off, 64);
  if ((tid & 63) == 0) redd[tid >> 6] = s;
  __syncthreads();
  if (tid == 0) {
    double t = 0.0;
#pragma unroll
    for (int w = 0; w < 16; ++w) t += redd[w];
    SumE0[n] = t;
  }
}

// ---------------------------------------------------------------------------
// K4: ctxpart[ks][n][d] = sum over ks's K-range of exp(L0-M0)*memory (split-4)
// ---------------------------------------------------------------------------
__global__ __launch_bounds__(256) void k_ctxpart(
    const float* __restrict__ L0, const float* __restrict__ M0,
    const float* __restrict__ mem, float* __restrict__ ctxp) {
  int ks = blockIdx.x;
  int n0 = blockIdx.y * 32;
  int d0 = blockIdx.z * 64;
  int tid = threadIdx.x;
  __shared__ float Et[64 * 32];
  __shared__ float mTl[64 * 64];
  __shared__ float Msh[32];
  if (tid < 32) Msh[tid] = M0[n0 + tid];
  const int lane = tid & 63, wv = tid >> 6;
  const int tx = lane & 15, ty = lane >> 4;
  const int ng = (wv * 4 + ty) * 2;
  const int dg = tx * 4;
  float acc[2][4] = {{0, 0, 0, 0}, {0, 0, 0, 0}};
  for (int kc = 0; kc < 8; ++kc) {
    int kb = ks * 512 + kc * 64;
    __syncthreads();
#pragma unroll
    for (int j = 0; j < 8; ++j) {
      int ii = tid + 256 * j;
      int nr = ii & 31, kk = ii >> 5;
      Et[kk * 32 + nr] = expf(L0[(n0 + nr) * M_ + kb + kk] - Msh[nr]);
    }
    {
      int r = tid & 63, c = tid >> 6;
#pragma unroll
      for (int j = 0; j < 4; ++j) {
        int c4 = (c * 4 + j) * 4;
        *(float4*)&mTl[r * 64 + c4] = *(const float4*)&mem[(kb + r) * D_ + d0 + c4];
      }
    }
    __syncthreads();
#pragma unroll 4
    for (int kk = 0; kk < 64; ++kk) {
      float4 mv = *(const float4*)&mTl[kk * 64 + dg];
      float e0v = Et[kk * 32 + ng], e1v = Et[kk * 32 + ng + 1];
      acc[0][0] = fmaf(e0v, mv.x, acc[0][0]); acc[0][1] = fmaf(e0v, mv.y, acc[0][1]);
      acc[0][2] = fmaf(e0v, mv.z, acc[0][2]); acc[0][3] = fmaf(e0v, mv.w, acc[0][3]);
      acc[1][0] = fmaf(e1v, mv.x, acc[1][0]); acc[1][1] = fmaf(e1v, mv.y, acc[1][1]);
      acc[1][2] = fmaf(e1v, mv.z, acc[1][2]); acc[1][3] = fmaf(e1v, mv.w, acc[1][3]);
    }
  }
#pragma unroll
  for (int i = 0; i < 2; ++i) {
    int n = n0 + ng + i;
    *(float4*)&ctxp[((size_t)ks * N_ + n) * D_ + d0 + dg] =
        make_float4(acc[i][0], acc[i][1], acc[i][2], acc[i][3]);
  }
}

// ---------------------------------------------------------------------------
// K5: the scan. One block/batch, 1024 threads, 3 barriers/step.
// A1 (waves 0-14): half-wave groups — 2 slots/wave/iteration (~9 iters vs 17),
//   5-level butterfly within 32 lanes, qt/g/x chunks hoisted to registers
//   (no per-iteration LDS broadcasts). Wave 15: candprep + prefetch.
// PB (waves 0-14): dual GEMV (17-row strips); wave15: denom + top-8 selection.
// PC: finalize out/gate.
// ---------------------------------------------------------------------------
__global__ __launch_bounds__(1024, 4) void k_scan(
    const float* __restrict__ x, const float* __restrict__ mem0,
    const float* __restrict__ Wv, const float* __restrict__ bv,
    const float* __restrict__ WvWgB, const float* __restrict__ bvg,
    const float* __restrict__ qt, const float* __restrict__ qbk,
    const float* __restrict__ xgp, const float* __restrict__ L0,
    const float* __restrict__ M0, const double* __restrict__ SumE0,
    const float* __restrict__ ctxp, const float* __restrict__ topv,
    const int* __restrict__ topi, float* __restrict__ memcur,
    float* __restrict__ out) {
  const int b = blockIdx.x;
  const int tid = threadIdx.x;
  const int lane = tid & 63;
  const int wvid = tid >> 6;

  __shared__ short tpos[M_];                      // 4 KB
  __shared__ unsigned int descL[NSLOT];           // 1 KB: m | fresh<<11 | pend<<12
  __shared__ float candV[NCAND];                  // 2 KB
  __shared__ int candI[NCAND];                    // 2 KB
  __shared__ float diffA[NSLOT];                  // 1 KB
  __shared__ float dpart[15][D_];                 // 15 KB
  __shared__ float fpart[15][D_];                 // 15 KB
  __shared__ float fpart2[15][D_];                // 15 KB
  __shared__ float qt_s[2][D_], xt_s[2][D_];      // 4 KB
  __shared__ float CTX0_s[D_], xgp_s[D_], g_s[D_], bv_s[D_], bvg_s[D_];  // 5 KB
  __shared__ float wvlds[(256 - CACHE0) * D_];    // 64 KB
  __shared__ float Msc[S_], qbks[S_];
  __shared__ double sum0s[S_];
  __shared__ float inv_esum;
  __shared__ int Tcount;
  __shared__ int selIdx[TK];

  const float4* mem04 = (const float4*)mem0;
  const float4* mcur4c = (const float4*)memcur;
  float4* mcur4 = (float4*)memcur;
  const float4* Wv4 = (const float4*)Wv;
  const float4* Wg4 = (const float4*)WvWgB;
  const float4* qt4 = (const float4*)qt;
  const float4* x4 = (const float4*)x;
  const float4* ctxp4 = (const float4*)ctxp;
  const float4* xgp4 = (const float4*)xgp;
  const float4* wvlds4 = (const float4*)wvlds;

  // ---- pinned Wv strip: wave w (w<15) holds rows [17w, 17w+17) (+row 255 for w=14)
  float4 wreg[18];
  {
    const int kbase = 17 * wvid;
    if (wvid < 15) {
#pragma unroll
      for (int j = 0; j < 17; ++j) wreg[j] = Wv4[(size_t)(kbase + j) * 64 + lane];
      wreg[17] = (wvid == 14) ? Wv4[(size_t)255 * 64 + lane] : wreg[16];
    }
  }

  // ---- one-time preload
  for (int m = tid; m < M_; m += 1024) tpos[m] = -1;
  for (int s = tid; s < NSLOT; s += 1024) descL[s] = 0;
  for (int i = tid; i < (256 - CACHE0) * 64; i += 1024)
    ((float4*)wvlds)[i] = Wg4[(size_t)CACHE0 * 64 + i];
  if (tid < NCAND) {
    candV[tid] = -INFINITY;
    candI[tid] = 0x7FFFFFFF;
  }
  if (tid < S_) {
    Msc[tid] = M0[tid * B_ + b];
    qbks[tid] = qbk[tid * B_ + b];
    sum0s[tid] = SumE0[tid * B_ + b];
  } else if (tid >= 64 && tid < 64 + D_) {
    int d = tid - 64;
    bv_s[d] = bv[d];
    bvg_s[d] = bvg[d];
  } else if (tid >= 512 && tid < 576) {
    int j = tid - 512;
    ((float4*)qt_s[0])[j] = qt4[(size_t)b * 64 + j];  // qt(t=0)
  } else if (tid >= 576 && tid < 640) {
    int j = tid - 576;
    ((float4*)xt_s[0])[j] = x4[(size_t)(b * S_) * 64 + j];  // x(t=0)
  }
  if (tid == 0) Tcount = 0;
  __syncthreads();

  for (int t = 0; t < S_; ++t) {
    const int n = t * B_ + b;
    const int par = t & 1;
    const int Tc = Tcount;
    const float c0 = Msc[t];
    const float qb = qbks[t];

    // ===== A1: half-wave lazy-update + dot + correction (waves 0-14) =====
    if (wvid < 15) {
      const int sub = lane & 31;
      const int h = lane >> 5;  // group id: my slot index = sbase + 15*h
      // register-hoisted chunks: lane covers row float4 indices {sub, sub+32}
      const float4 qvA = ((const float4*)qt_s[par])[sub];
      const float4 qvB = ((const float4*)qt_s[par])[sub + 32];
      const float4 gA = ((const float4*)g_s)[sub];
      const float4 gB = ((const float4*)g_s)[sub + 32];
      const float4 xpA = ((const float4*)xt_s[par ^ 1])[sub];
      const float4 xpB = ((const float4*)xt_s[par ^ 1])[sub + 32];
      float4 accA = make_float4(0.f, 0.f, 0.f, 0.f);
      float4 accB = make_float4(0.f, 0.f, 0.f, 0.f);

      int sbase = wvid;
      int s = sbase + 15 * h;
      bool act = (s < Tc);
      unsigned int dsc_c = 0;
      float4 mA_c = make_float4(0.f, 0.f, 0.f, 0.f), mB_c = mA_c, oA_c = mA_c, oB_c = mA_c;
      float l0_c = 0.f;
      if (act) {
        dsc_c = descL[s];
        const int m = dsc_c & 2047;
        oA_c = mem04[(size_t)m * 64 + sub];
        oB_c = mem04[(size_t)m * 64 + sub + 32];
        const bool fM0 = (dsc_c & (1u << 12)) && (dsc_c & (1u << 11));
        mA_c = fM0 ? oA_c : mcur4c[(size_t)(b * NSLOT + s) * 64 + sub];
        mB_c = fM0 ? oB_c : mcur4c[(size_t)(b * NSLOT + s) * 64 + sub + 32];
        l0_c = L0[(size_t)n * M_ + m];
      }
      while (sbase < Tc) {
        const int sb2 = sbase + 30;
        const int s2 = sb2 + 15 * h;
        const bool act2 = (s2 < Tc);
        unsigned int dsc_n = 0;
        float4 mA_n = make_float4(0.f, 0.f, 0.f, 0.f), mB_n = mA_n, oA_n = mA_n, oB_n = mA_n;
        float l0_n = 0.f;
        if (act2) {
          dsc_n = descL[s2];
          const int mn = dsc_n & 2047;
          oA_n = mem04[(size_t)mn * 64 + sub];
          oB_n = mem04[(size_t)mn * 64 + sub + 32];
          const bool fM0 = (dsc_n & (1u << 12)) && (dsc_n & (1u << 11));
          mA_n = fM0 ? oA_n : mcur4c[(size_t)(b * NSLOT + s2) * 64 + sub];
          mB_n = fM0 ? oB_n : mcur4c[(size_t)(b * NSLOT + s2) * 64 + sub + 32];
          l0_n = L0[(size_t)n * M_ + mn];
        }
        if (act) {
          const int m = dsc_c & 2047;
          if (dsc_c & (1u << 12)) {  // pending update: apply, writeback
            mA_c.x = fmaf(gA.x, xpA.x - mA_c.x, mA_c.x);
            mA_c.y = fmaf(gA.y, xpA.y - mA_c.y, mA_c.y);
            mA_c.z = fmaf(gA.z, xpA.z - mA_c.z, mA_c.z);
            mA_c.w = fmaf(gA.w, xpA.w - mA_c.w, mA_c.w);
            mB_c.x = fmaf(gB.x, xpB.x - mB_c.x, mB_c.x);
            mB_c.y = fmaf(gB.y, xpB.y - mB_c.y, mB_c.y);
            mB_c.z = fmaf(gB.z, xpB.z - mB_c.z, mB_c.z);
            mB_c.w = fmaf(gB.w, xpB.w - mB_c.w, mB_c.w);
            mcur4[(size_t)(b * NSLOT + s) * 64 + sub] = mA_c;
            mcur4[(size_t)(b * NSLOT + s) * 64 + sub + 32] = mB_c;
            if (sub == 0) descL[s] = (unsigned int)m;
          }
          float p = mA_c.x * qvA.x;
          p = fmaf(mA_c.y, qvA.y, p);
          p = fmaf(mA_c.z, qvA.z, p);
          p = fmaf(mA_c.w, qvA.w, p);
          p = fmaf(mB_c.x, qvB.x, p);
          p = fmaf(mB_c.y, qvB.y, p);
          p = fmaf(mB_c.z, qvB.z, p);
          p = fmaf(mB_c.w, qvB.w, p);
          p += __shfl_xor(p, 1, 64);
          p += __shfl_xor(p, 2, 64);
          p += __shfl_xor(p, 4, 64);
          p += __shfl_xor(p, 8, 64);
          p += __shfl_xor(p, 16, 64);
          const float cur = (p + qb) * 0.0625f;
          const float ce = expf(cur - c0);
          const float e0 = expf(l0_c - c0);
          accA.x = fmaf(ce, mA_c.x, fmaf(-e0, oA_c.x, accA.x));
          accA.y = fmaf(ce, mA_c.y, fmaf(-e0, oA_c.y, accA.y));
          accA.z = fmaf(ce, mA_c.z, fmaf(-e0, oA_c.z, accA.z));
          accA.w = fmaf(ce, mA_c.w, fmaf(-e0, oA_c.w, accA.w));
          accB.x = fmaf(ce, mB_c.x, fmaf(-e0, oB_c.x, accB.x));
          accB.y = fmaf(ce, mB_c.y, fmaf(-e0, oB_c.y, accB.y));
          accB.z = fmaf(ce, mB_c.z, fmaf(-e0, oB_c.z, accB.z));
          accB.w = fmaf(ce, mB_c.w, fmaf(-e0, oB_c.w, accB.w));
          if (sub == 0) {
            diffA[s] = ce - e0;
            candV[s] = cur;
            candI[s] = m;
          }
        }
        dsc_c = dsc_n;
        mA_c = mA_n; mB_c = mB_n; oA_c = oA_n; oB_c = oB_n;
        l0_c = l0_n;
        s = s2;
        act = act2;
        sbase = sb2;
      }
      // cross-group sum, then write dpart (group0 -> idx sub, group1 -> sub+32)
      accA.x += __shfl_xor(accA.x, 32, 64);
      accA.y += __shfl_xor(accA.y, 32, 64);
      accA.z += __shfl_xor(accA.z, 32, 64);
      accA.w += __shfl_xor(accA.w, 32, 64);
      accB.x += __shfl_xor(accB.x, 32, 64);
      accB.y += __shfl_xor(accB.y, 32, 64);
      accB.z += __shfl_xor(accB.z, 32, 64);
      accB.w += __shfl_xor(accB.w, 32, 64);
      if (h == 0)
        ((float4*)dpart[wvid])[sub] = accA;
      else
        ((float4*)dpart[wvid])[sub + 32] = accB;
    } else {
      // wave 15: candidate prep + per-step prefetches
#pragma unroll
      for (int jj = 0; jj < 4; ++jj) {
        const int j = lane + jj * 64;
        const int ii = topi[n * TOPC + j];
        const bool fresh = (tpos[ii] < 0);
        candV[NSLOT + j] = fresh ? topv[n * TOPC + j] : -INFINITY;
        candI[NSLOT + j] = fresh ? ii : 0x7FFFFFFF;
      }
      const float4 c0v = ctxp4[(size_t)(0 * N_ + n) * 64 + lane];
      const float4 c1v = ctxp4[(size_t)(1 * N_ + n) * 64 + lane];
      const float4 c2v = ctxp4[(size_t)(2 * N_ + n) * 64 + lane];
      const float4 c3v = ctxp4[(size_t)(3 * N_ + n) * 64 + lane];
      ((float4*)CTX0_s)[lane] = make_float4(c0v.x + c1v.x + c2v.x + c3v.x,
                                            c0v.y + c1v.y + c2v.y + c3v.y,
                                            c0v.z + c1v.z + c2v.z + c3v.z,
                                            c0v.w + c1v.w + c2v.w + c3v.w);
      ((float4*)xgp_s)[lane] = xgp4[(size_t)n * 64 + lane];
      if (t + 1 < S_) {
        ((float4*)qt_s[par ^ 1])[lane] = qt4[(size_t)(n + B_) * 64 + lane];
        ((float4*)xt_s[par ^ 1])[lane] = x4[(size_t)(b * S_ + t + 1) * 64 + lane];
      }
    }
    __syncthreads();  // B1

    // ===== PB: GEMV (waves 0-14) || denom + selection (wave 15)
    if (wvid < 15) {
      const int kbase = 17 * wvid;
      const int nr = (wvid == 14) ? 18 : 17;
      float mynum = 0.f;
      if (lane < nr) {
        const int k = (lane == 17) ? 255 : (kbase + lane);
        float nv = CTX0_s[k];
#pragma unroll
        for (int p = 0; p < 15; ++p) nv += dpart[p][k];
        mynum = nv;
      }
      float4 a1 = make_float4(0.f, 0.f, 0.f, 0.f);
      float4 a2 = make_float4(0.f, 0.f, 0.f, 0.f);
#pragma unroll
      for (int j = 0; j < 17; ++j) {
        const float nv = __int_as_float(__builtin_amdgcn_readlane(__float_as_int(mynum), j));
        a1.x = fmaf(nv, wreg[j].x, a1.x); a1.y = fmaf(nv, wreg[j].y, a1.y);
        a1.z = fmaf(nv, wreg[j].z, a1.z); a1.w = fmaf(nv, wreg[j].w, a1.w);
        const int r = kbase + j;
        const float4 w4 = (r >= CACHE0) ? wvlds4[(size_t)(r - CACHE0) * 64 + lane]
                                        : Wg4[(size_t)r * 64 + lane];
        a2.x = fmaf(nv, w4.x, a2.x); a2.y = fmaf(nv, w4.y, a2.y);
        a2.z = fmaf(nv, w4.z, a2.z); a2.w = fmaf(nv, w4.w, a2.w);
      }
      if (wvid == 14) {
        const float nv = __int_as_float(__builtin_amdgcn_readlane(__float_as_int(mynum), 17));
        a1.x = fmaf(nv, wreg[17].x, a1.x); a1.y = fmaf(nv, wreg[17].y, a1.y);
        a1.z = fmaf(nv, wreg[17].z, a1.z); a1.w = fmaf(nv, wreg[17].w, a1.w);
        const float4 w4 = wvlds4[(size_t)(255 - CACHE0) * 64 + lane];
        a2.x = fmaf(nv, w4.x, a2.x); a2.y = fmaf(nv, w4.y, a2.y);
        a2.z = fmaf(nv, w4.z, a2.z); a2.w = fmaf(nv, w4.w, a2.w);
      }
      ((float4*)fpart[wvid])[lane] = a1;
      ((float4*)fpart2[wvid])[lane] = a2;
    } else {
      double ds = 0.0;
      for (int s = lane; s < Tc; s += 64) ds += (double)diffA[s];
      for (int off = 32; off > 0; off >>= 1) ds += __shfl_down(ds, off, 64);
      if (lane == 0) inv_esum = (float)(1.0 / (sum0s[t] + ds));
      if (t + 1 < S_) {
        float cv[8];
        int ci[8];
#pragma unroll
        for (int j = 0; j < 8; ++j) {
          cv[j] = candV[lane * 8 + j];
          ci[j] = candI[lane * 8 + j];
        }
        for (int r = 0; r < TK; ++r) {
          float bvv = cv[0];
          int bii = ci[0];
#pragma unroll
          for (int j = 1; j < 8; ++j)
            if (cv[j] > bvv || (cv[j] == bvv && ci[j] < bii)) { bvv = cv[j]; bii = ci[j]; }
#pragma unroll
          for (int off = 1; off < 64; off <<= 1) {
            float ov = __shfl_xor(bvv, off, 64);
            int oi = __shfl_xor(bii, off, 64);
            if (ov > bvv || (ov == bvv && oi < bii)) { bvv = ov; bii = oi; }
          }
          if (lane == 0) selIdx[r] = bii;
#pragma unroll
          for (int j = 0; j < 8; ++j)
            if (ci[j] == bii) { cv[j] = -INFINITY; ci[j] = 0x7FFFFFFF; }
        }
        if (lane == 0) {
          int tc = Tcount;
          for (int k = 0; k < TK; ++k) {
            const int m = selIdx[k];
            int s = tpos[m];
            unsigned int fresh = 0;
            if (s < 0) {
              s = tc++;
              tpos[m] = (short)s;
              candI[s] = m;
              fresh = 1;
            }
            descL[s] = (unsigned int)m | (fresh << 11) | (1u << 12);
          }
          Tcount = tc;
        }
      }
    }
    __syncthreads();  // B2

    // ===== PC: finalize out & gate =====
    if (tid < D_) {
      float o = 0.f;
#pragma unroll
      for (int p = 0; p < 15; ++p) o += fpart[p][tid];
      o = o * inv_esum + bv_s[tid];
      out[((size_t)b * S_ + t) * D_ + tid] = o;
    } else if (tid < 2 * D_) {
      const int d = tid - D_;
      float gg = 0.f;
#pragma unroll
      for (int p = 0; p < 15; ++p) gg += fpart2[p][d];
      const float gin = xgp_s[d] + gg * inv_esum + bvg_s[d];
      g_s[d] = 1.0f / (1.0f + expf(-gin));
    }
    __syncthreads();  // B3
  }
}

// ---------------------------------------------------------------------------
extern "C" void kernel_launch(void* const* d_in, const int* in_sizes, int n_in,
                              void* d_out, int out_size, void* d_ws, size_t ws_size,
                              hipStream_t stream) {
  const float* x = (const float*)d_in[0];
  const float* mem0 = (const float*)d_in[1];
  const float* Wq = (const float*)d_in[2];
  const float* bq = (const float*)d_in[3];
  const float* Wk = (const float*)d_in[4];
  const float* bk = (const float*)d_in[5];
  const float* Wv = (const float*)d_in[6];
  const float* bv = (const float*)d_in[7];
  const float* Wg = (const float*)d_in[8];
  const float* bg = (const float*)d_in[9];
  float* out = (float*)d_out;
  float* ws = (float*)d_ws;

  size_t o = 0;
  float* WkT = ws + o;    o += (size_t)D_ * D_;
  float* qt = ws + o;     o += (size_t)N_ * D_;
  float* qbk = ws + o;    o += N_;
  float* xgp = ws + o;    o += (size_t)N_ * D_;
  float* L0 = ws + o;     o += (size_t)N_ * M_;
  float* M0 = ws + o;     o += N_;
  double* SumE0 = (double*)(ws + o); o += 2 * N_;
  float* ctxp = ws + o;   o += (size_t)KSPLIT * N_ * D_;
  float* topv = ws + o;   o += (size_t)N_ * TOPC;
  int* topi = (int*)(ws + o); o += (size_t)N_ * TOPC;
  float* WvWgB = ws + o;  o += (size_t)D_ * D_;
  float* bvg = ws + o;    o += D_;
  float* memcur = ws + o; o += (size_t)B_ * NSLOT * D_;

  k_wvwgT<<<dim3(81), dim3(256), 0, stream>>>(Wv, Wg, bv, bg, Wk, WvWgB, bvg, WkT);
  k_qproj<<<dim3(N_), dim3(256), 0, stream>>>(x, Wq, bq, bk, WkT, Wg, qt, qbk, xgp);
  k_L0<<<dim3(M_ / 64, N_ / 64), dim3(256), 0, stream>>>(qt, mem0, qbk, L0);
  k_sortstats<<<dim3(N_), dim3(1024), 0, stream>>>(L0, topv, topi, M0, SumE0);
  k_ctxpart<<<dim3(KSPLIT, N_ / 32, D_ / 64), dim3(256), 0, stream>>>(L0, M0, mem0, ctxp);
  k_scan<<<dim3(B_), dim3(1024), 0, stream>>>(x, mem0, Wv, bv, WvWgB, bvg, qt, qbk, xgp,
                                              L0, M0, SumE0, ctxp, topv, topi, memcur, out);
}

// Round 17
// 612.463 us; speedup vs baseline: 1.1378x; 1.1378x over previous
//
#include <hip/hip_runtime.h>
#include <math.h>

// Problem constants
constexpr int B_ = 8, S_ = 32, D_ = 256, M_ = 2048;
constexpr int N_ = S_ * B_;          // 256 (t,b) pairs, n = t*B + b
constexpr int TK = 8;                // TOPK
constexpr int NSLOT = 256;           // max distinct touched rows (8*31=248)
constexpr int TOPC = 256;            // precomputed top-C of L0 per (t,b)
constexpr int NCAND = NSLOT + TOPC;  // 512
constexpr int KSPLIT = 4;            // ctxpart split-K
constexpr int CACHE0 = 192;          // WvWgB rows [CACHE0,256) cached in LDS (64KB)

// ---------------------------------------------------------------------------
// K0: blocks 0..15: WvWgB[i][d] = sum_j Wv[i][j]*Wg[D+j][d]
//     block 16:     bvg[d] = bg[d] + sum_j bv[j]*Wg[D+j][d]
//     blocks 17..80: WkT[j][i] = Wk[i][j]
// ---------------------------------------------------------------------------
__global__ __launch_bounds__(256) void k_wvwgT(const float* __restrict__ Wv,
                                               const float* __restrict__ Wg,
                                               const float* __restrict__ bv,
                                               const float* __restrict__ bg,
                                               const float* __restrict__ Wk,
                                               float* __restrict__ WvWgB,
                                               float* __restrict__ bvg,
                                               float* __restrict__ WkT) {
  int blk = blockIdx.x;
  int tid = threadIdx.x;
  if (blk >= 17) {
    __shared__ float tile[32][33];
    int bb = blk - 17;
    int bx = bb & 7, by = bb >> 3;
    int x0 = bx * 32, y0 = by * 32;
    int tx = tid & 31, ty = tid >> 5;
    for (int j = ty; j < 32; j += 8) tile[j][tx] = Wk[(y0 + j) * D_ + x0 + tx];
    __syncthreads();
    for (int j = ty; j < 32; j += 8) WkT[(x0 + j) * D_ + y0 + tx] = tile[tx][j];
    return;
  }
  if (blk == 16) {
    float a = bg[tid];
#pragma unroll 8
    for (int j = 0; j < D_; ++j) a = fmaf(bv[j], Wg[(size_t)(D_ + j) * D_ + tid], a);
    bvg[tid] = a;
    return;
  }
  int i0 = (blk & 3) * 64, d0 = (blk >> 2) * 64;
  __shared__ float At[64 * 64];  // [j][i]
  __shared__ float Bt[64 * 64];  // [j][d]
  const int r = tid & 63, c = tid >> 6;
  const int lane = tid & 63, wvv = tid >> 6;
  const int tx = lane & 15, ty = lane >> 4;
  const int dg = tx * 4, ig = (wvv * 4 + ty) * 4;
  float acc[4][4];
#pragma unroll
  for (int i = 0; i < 4; ++i)
#pragma unroll
    for (int j = 0; j < 4; ++j) acc[i][j] = 0.f;
  for (int kc = 0; kc < 4; ++kc) {
    __syncthreads();
#pragma unroll
    for (int it = 0; it < 4; ++it) {
      int jq = (c * 4 + it) * 4;
      float4 a = *(const float4*)&Wv[(i0 + r) * D_ + kc * 64 + jq];
      At[(jq + 0) * 64 + r] = a.x; At[(jq + 1) * 64 + r] = a.y;
      At[(jq + 2) * 64 + r] = a.z; At[(jq + 3) * 64 + r] = a.w;
      *(float4*)&Bt[r * 64 + jq] =
          *(const float4*)&Wg[(size_t)(D_ + kc * 64 + r) * D_ + d0 + jq];
    }
    __syncthreads();
#pragma unroll 4
    for (int j = 0; j < 64; ++j) {
      float4 av = *(const float4*)&At[j * 64 + ig];
      float4 bv4 = *(const float4*)&Bt[j * 64 + dg];
      acc[0][0] = fmaf(av.x, bv4.x, acc[0][0]); acc[0][1] = fmaf(av.x, bv4.y, acc[0][1]);
      acc[0][2] = fmaf(av.x, bv4.z, acc[0][2]); acc[0][3] = fmaf(av.x, bv4.w, acc[0][3]);
      acc[1][0] = fmaf(av.y, bv4.x, acc[1][0]); acc[1][1] = fmaf(av.y, bv4.y, acc[1][1]);
      acc[1][2] = fmaf(av.y, bv4.z, acc[1][2]); acc[1][3] = fmaf(av.y, bv4.w, acc[1][3]);
      acc[2][0] = fmaf(av.z, bv4.x, acc[2][0]); acc[2][1] = fmaf(av.z, bv4.y, acc[2][1]);
      acc[2][2] = fmaf(av.z, bv4.z, acc[2][2]); acc[2][3] = fmaf(av.z, bv4.w, acc[2][3]);
      acc[3][0] = fmaf(av.w, bv4.x, acc[3][0]); acc[3][1] = fmaf(av.w, bv4.y, acc[3][1]);
      acc[3][2] = fmaf(av.w, bv4.z, acc[3][2]); acc[3][3] = fmaf(av.w, bv4.w, acc[3][3]);
    }
  }
#pragma unroll
  for (int i = 0; i < 4; ++i)
    *(float4*)&WvWgB[(size_t)(i0 + ig + i) * D_ + d0 + dg] =
        make_float4(acc[i][0], acc[i][1], acc[i][2], acc[i][3]);
}

// ---------------------------------------------------------------------------
// K1: per n=(t,b): q = xt@Wq+bq ; qt[d]=sum_i q[i]*WkT[i][d] ; qbk = q.bk ;
//     xgpre = xt @ Wg[0:D,:]
// ---------------------------------------------------------------------------
__global__ __launch_bounds__(256) void k_qproj(
    const float* __restrict__ x, const float* __restrict__ Wq,
    const float* __restrict__ bq, const float* __restrict__ bk,
    const float* __restrict__ WkT, const float* __restrict__ Wg,
    float* __restrict__ qt, float* __restrict__ qbk, float* __restrict__ xgp) {
  int n = blockIdx.x, tid = threadIdx.x;
  int t = n / B_, b = n % B_;
  __shared__ float xr[D_], qsh[D_];
  __shared__ float red[4];
  xr[tid] = x[(b * S_ + t) * D_ + tid];
  __syncthreads();
  float accq = bq[tid], accg = 0.f;
#pragma unroll 8
  for (int i = 0; i < D_; ++i) {
    float xv = xr[i];
    accq = fmaf(xv, Wq[i * D_ + tid], accq);
    accg = fmaf(xv, Wg[i * D_ + tid], accg);
  }
  qsh[tid] = accq;
  xgp[n * D_ + tid] = accg;
  float p = accq * bk[tid];
  for (int off = 32; off > 0; off >>= 1) p += __shfl_down(p, off, 64);
  if ((tid & 63) == 0) red[tid >> 6] = p;
  __syncthreads();
  float acct = 0.f;
#pragma unroll 8
  for (int i = 0; i < D_; ++i) acct = fmaf(qsh[i], WkT[i * D_ + tid], acct);
  qt[n * D_ + tid] = acct;
  if (tid == 0) qbk[n] = red[0] + red[1] + red[2] + red[3];
}

// ---------------------------------------------------------------------------
// K2: L0[n][m] = (memory[m] . qt[n] + qbk[n]) / 16
// ---------------------------------------------------------------------------
__global__ __launch_bounds__(256) void k_L0(
    const float* __restrict__ qt, const float* __restrict__ mem,
    const float* __restrict__ qbk, float* __restrict__ L0) {
  __shared__ float qtT[64 * 64];
  __shared__ float mT[64 * 64];
  const int tid = threadIdx.x;
  const int m0 = blockIdx.x * 64, n0 = blockIdx.y * 64;
  const int r = tid & 63, c = tid >> 6;
  const int lane = tid & 63, wv = tid >> 6;
  const int tx = lane & 15, ty = lane >> 4;
  const int mg = tx * 4, ng = (wv * 4 + ty) * 4;
  float acc[4][4];
#pragma unroll
  for (int i = 0; i < 4; ++i)
#pragma unroll
    for (int j = 0; j < 4; ++j) acc[i][j] = 0.f;
  for (int kc = 0; kc < 4; ++kc) {
    __syncthreads();
#pragma unroll
    for (int it = 0; it < 4; ++it) {
      int kq = (c * 4 + it) * 4;
      float4 a = *(const float4*)&qt[(n0 + r) * D_ + kc * 64 + kq];
      qtT[(kq + 0) * 64 + r] = a.x; qtT[(kq + 1) * 64 + r] = a.y;
      qtT[(kq + 2) * 64 + r] = a.z; qtT[(kq + 3) * 64 + r] = a.w;
      float4 bm = *(const float4*)&mem[(m0 + r) * D_ + kc * 64 + kq];
      mT[(kq + 0) * 64 + r] = bm.x; mT[(kq + 1) * 64 + r] = bm.y;
      mT[(kq + 2) * 64 + r] = bm.z; mT[(kq + 3) * 64 + r] = bm.w;
    }
    __syncthreads();
#pragma unroll 4
    for (int k = 0; k < 64; ++k) {
      float4 av = *(const float4*)&qtT[k * 64 + ng];
      float4 bv4 = *(const float4*)&mT[k * 64 + mg];
      acc[0][0] = fmaf(av.x, bv4.x, acc[0][0]); acc[0][1] = fmaf(av.x, bv4.y, acc[0][1]);
      acc[0][2] = fmaf(av.x, bv4.z, acc[0][2]); acc[0][3] = fmaf(av.x, bv4.w, acc[0][3]);
      acc[1][0] = fmaf(av.y, bv4.x, acc[1][0]); acc[1][1] = fmaf(av.y, bv4.y, acc[1][1]);
      acc[1][2] = fmaf(av.y, bv4.z, acc[1][2]); acc[1][3] = fmaf(av.y, bv4.w, acc[1][3]);
      acc[2][0] = fmaf(av.z, bv4.x, acc[2][0]); acc[2][1] = fmaf(av.z, bv4.y, acc[2][1]);
      acc[2][2] = fmaf(av.z, bv4.z, acc[2][2]); acc[2][3] = fmaf(av.z, bv4.w, acc[2][3]);
      acc[3][0] = fmaf(av.w, bv4.x, acc[3][0]); acc[3][1] = fmaf(av.w, bv4.y, acc[3][1]);
      acc[3][2] = fmaf(av.w, bv4.z, acc[3][2]); acc[3][3] = fmaf(av.w, bv4.w, acc[3][3]);
    }
  }
#pragma unroll
  for (int i = 0; i < 4; ++i) {
    int n = n0 + ng + i;
    float qbv = qbk[n];
    float4 o;
    o.x = (acc[i][0] + qbv) * 0.0625f; o.y = (acc[i][1] + qbv) * 0.0625f;
    o.z = (acc[i][2] + qbv) * 0.0625f; o.w = (acc[i][3] + qbv) * 0.0625f;
    *(float4*)&L0[n * M_ + m0 + mg] = o;
  }
}

// ---------------------------------------------------------------------------
// K3: fused full bitonic sort (desc, tie idx asc) + top-256 + M0 + SumE0(fp64)
// 1024 threads: one compare-exchange per thread per stage (M_/2 = 1024).
// ---------------------------------------------------------------------------
__global__ __launch_bounds__(1024) void k_sortstats(const float* __restrict__ L0,
                                                    float* __restrict__ topv,
                                                    int* __restrict__ topi,
                                                    float* __restrict__ M0,
                                                    double* __restrict__ SumE0) {
  int n = blockIdx.x, tid = threadIdx.x;
  __shared__ float v[M_];
  __shared__ short ix[M_];
  __shared__ double redd[16];
  for (int m = tid; m < M_; m += 1024) {
    v[m] = L0[(size_t)n * M_ + m];
    ix[m] = (short)m;
  }
  __syncthreads();
  for (int size = 2; size <= M_; size <<= 1) {
    for (int stride = size >> 1; stride > 0; stride >>= 1) {
      const int i = tid;  // exactly M_/2 pairs
      const int pos = 2 * i - (i & (stride - 1));
      const int j = pos + stride;
      const bool desc = ((pos & size) == 0);
      const float va = v[pos], vb2 = v[j];
      const short ia = ix[pos], ib = ix[j];
      const bool aG = (va > vb2) || (va == vb2 && ia < ib);
      if (desc ? !aG : aG) { v[pos] = vb2; v[j] = va; ix[pos] = ib; ix[j] = ia; }
      __syncthreads();
    }
  }
  if (tid < TOPC) {
    topv[n * TOPC + tid] = v[tid];
    topi[n * TOPC + tid] = (int)ix[tid];
  }
  float mx = v[0];
  if (tid == 0) M0[n] = mx;
  double s = 0.0;
  for (int m = tid; m < M_; m += 1024) s += (double)expf(v[m] - mx);
  for (int off = 32; off > 0; off >>= 1) s += __shfl_down(s, off, 64);
  if ((tid & 63) == 0) redd[tid >> 6] = s;
  __syncthreads();
  if (tid == 0) {
    double t = 0.0;
#pragma unroll
    for (int w = 0; w < 16; ++w) t += redd[w];
    SumE0[n] = t;
  }
}

// ---------------------------------------------------------------------------
// K4: ctxpart[ks][n][d] = sum over ks's K-range of exp(L0-M0)*memory (split-4)
// ---------------------------------------------------------------------------
__global__ __launch_bounds__(256) void k_ctxpart(
    const float* __restrict__ L0, const float* __restrict__ M0,
    const float* __restrict__ mem, float* __restrict__ ctxp) {
  int ks = blockIdx.x;
  int n0 = blockIdx.y * 32;
  int d0 = blockIdx.z * 64;
  int tid = threadIdx.x;
  __shared__ float Et[64 * 32];
  __shared__ float mTl[64 * 64];
  __shared__ float Msh[32];
  if (tid < 32) Msh[tid] = M0[n0 + tid];
  const int lane = tid & 63, wv = tid >> 6;
  const int tx = lane & 15, ty = lane >> 4;
  const int ng = (wv * 4 + ty) * 2;
  const int dg = tx * 4;
  float acc[2][4] = {{0, 0, 0, 0}, {0, 0, 0, 0}};
  for (int kc = 0; kc < 8; ++kc) {
    int kb = ks * 512 + kc * 64;
    __syncthreads();
#pragma unroll
    for (int j = 0; j < 8; ++j) {
      int ii = tid + 256 * j;
      int nr = ii & 31, kk = ii >> 5;
      Et[kk * 32 + nr] = expf(L0[(n0 + nr) * M_ + kb + kk] - Msh[nr]);
    }
    {
      int r = tid & 63, c = tid >> 6;
#pragma unroll
      for (int j = 0; j < 4; ++j) {
        int c4 = (c * 4 + j) * 4;
        *(float4*)&mTl[r * 64 + c4] = *(const float4*)&mem[(kb + r) * D_ + d0 + c4];
      }
    }
    __syncthreads();
#pragma unroll 4
    for (int kk = 0; kk < 64; ++kk) {
      float4 mv = *(const float4*)&mTl[kk * 64 + dg];
      float e0v = Et[kk * 32 + ng], e1v = Et[kk * 32 + ng + 1];
      acc[0][0] = fmaf(e0v, mv.x, acc[0][0]); acc[0][1] = fmaf(e0v, mv.y, acc[0][1]);
      acc[0][2] = fmaf(e0v, mv.z, acc[0][2]); acc[0][3] = fmaf(e0v, mv.w, acc[0][3]);
      acc[1][0] = fmaf(e1v, mv.x, acc[1][0]); acc[1][1] = fmaf(e1v, mv.y, acc[1][1]);
      acc[1][2] = fmaf(e1v, mv.z, acc[1][2]); acc[1][3] = fmaf(e1v, mv.w, acc[1][3]);
    }
  }
#pragma unroll
  for (int i = 0; i < 2; ++i) {
    int n = n0 + ng + i;
    *(float4*)&ctxp[((size_t)ks * N_ + n) * D_ + d0 + dg] =
        make_float4(acc[i][0], acc[i][1], acc[i][2], acc[i][3]);
  }
}

// ---------------------------------------------------------------------------
// K5: the scan (R8 structure — measured best, 443µs). One block/batch,
// 1024 threads, 3 barriers/step. LDS ~132.5KB (CACHE0=192).
// A1 (waves 0-14): fused lazy-update + slot-dot + correction, wave-per-slot,
//                  depth-1 pipelined. Wave 15: candprep + prefetch.
// PB (waves 0-14): dual GEMV (17-row strips); wave15: denom + top-8 selection.
// PC: finalize out/gate.
// ---------------------------------------------------------------------------
__global__ __launch_bounds__(1024, 4) void k_scan(
    const float* __restrict__ x, const float* __restrict__ mem0,
    const float* __restrict__ Wv, const float* __restrict__ bv,
    const float* __restrict__ WvWgB, const float* __restrict__ bvg,
    const float* __restrict__ qt, const float* __restrict__ qbk,
    const float* __restrict__ xgp, const float* __restrict__ L0,
    const float* __restrict__ M0, const double* __restrict__ SumE0,
    const float* __restrict__ ctxp, const float* __restrict__ topv,
    const int* __restrict__ topi, float* __restrict__ memcur,
    float* __restrict__ out) {
  const int b = blockIdx.x;
  const int tid = threadIdx.x;
  const int lane = tid & 63;
  const int wvid = tid >> 6;

  __shared__ short tpos[M_];                      // 4 KB
  __shared__ unsigned int descL[NSLOT];           // 1 KB: m | fresh<<11 | pend<<12
  __shared__ float candV[NCAND];                  // 2 KB
  __shared__ int candI[NCAND];                    // 2 KB
  __shared__ float curE[NSLOT], e0sA[NSLOT], diffA[NSLOT];  // 3 KB
  __shared__ float dpart[15][D_];                 // 15 KB
  __shared__ float fpart[15][D_];                 // 15 KB
  __shared__ float fpart2[15][D_];                // 15 KB
  __shared__ float qt_s[2][D_], xt_s[2][D_];      // 4 KB
  __shared__ float CTX0_s[D_], xgp_s[D_], g_s[D_], bv_s[D_], bvg_s[D_];  // 5 KB
  __shared__ float wvlds[(256 - CACHE0) * D_];    // 64 KB
  __shared__ float Msc[S_], qbks[S_];
  __shared__ double sum0s[S_];
  __shared__ float inv_esum;
  __shared__ int Tcount;
  __shared__ int selIdx[TK];

  const float4* mem04 = (const float4*)mem0;
  const float4* mcur4c = (const float4*)memcur;
  float4* mcur4 = (float4*)memcur;
  const float4* Wv4 = (const float4*)Wv;
  const float4* Wg4 = (const float4*)WvWgB;
  const float4* qt4 = (const float4*)qt;
  const float4* x4 = (const float4*)x;
  const float4* ctxp4 = (const float4*)ctxp;
  const float4* xgp4 = (const float4*)xgp;
  const float4* wvlds4 = (const float4*)wvlds;

  // ---- pinned Wv strip: wave w (w<15) holds rows [17w, 17w+17) (+row 255 for w=14)
  float4 wreg[18];
  {
    const int kbase = 17 * wvid;
    if (wvid < 15) {
#pragma unroll
      for (int j = 0; j < 17; ++j) wreg[j] = Wv4[(size_t)(kbase + j) * 64 + lane];
      wreg[17] = (wvid == 14) ? Wv4[(size_t)255 * 64 + lane] : wreg[16];
    }
  }

  // ---- one-time preload
  for (int m = tid; m < M_; m += 1024) tpos[m] = -1;
  for (int s = tid; s < NSLOT; s += 1024) descL[s] = 0;
  for (int i = tid; i < (256 - CACHE0) * 64; i += 1024)
    ((float4*)wvlds)[i] = Wg4[(size_t)CACHE0 * 64 + i];
  if (tid < NCAND) {
    candV[tid] = -INFINITY;
    candI[tid] = 0x7FFFFFFF;
  }
  if (tid < S_) {
    Msc[tid] = M0[tid * B_ + b];
    qbks[tid] = qbk[tid * B_ + b];
    sum0s[tid] = SumE0[tid * B_ + b];
  } else if (tid >= 64 && tid < 64 + D_) {
    int d = tid - 64;
    bv_s[d] = bv[d];
    bvg_s[d] = bvg[d];
  } else if (tid >= 512 && tid < 576) {
    int j = tid - 512;
    ((float4*)qt_s[0])[j] = qt4[(size_t)b * 64 + j];  // qt(t=0)
  } else if (tid >= 576 && tid < 640) {
    int j = tid - 576;
    ((float4*)xt_s[0])[j] = x4[(size_t)(b * S_) * 64 + j];  // x(t=0)
  }
  if (tid == 0) Tcount = 0;
  __syncthreads();

  for (int t = 0; t < S_; ++t) {
    const int n = t * B_ + b;
    const int par = t & 1;
    const int Tc = Tcount;
    const float c0 = Msc[t];
    const float qb = qbks[t];

    // ===== A1: lazy-update + dot + correction (waves 0-14) =====
    if (wvid < 15) {
      const float4 qv = ((const float4*)qt_s[par])[lane];
      const float4 g4 = ((const float4*)g_s)[lane];
      const float4 xpv = ((const float4*)xt_s[par ^ 1])[lane];
      float4 acc = make_float4(0.f, 0.f, 0.f, 0.f);
      int s = wvid;
      unsigned int dsc_c = 0;
      float4 mc_c = make_float4(0.f, 0.f, 0.f, 0.f), mo_c = mc_c;
      float l0_c = 0.f;
      if (s < Tc) {
        dsc_c = descL[s];
        const int m = dsc_c & 2047;
        mo_c = mem04[(size_t)m * 64 + lane];
        const bool fromM0 = (dsc_c & (1u << 12)) && (dsc_c & (1u << 11));
        mc_c = fromM0 ? mo_c : mcur4c[(size_t)(b * NSLOT + s) * 64 + lane];
        l0_c = L0[(size_t)n * M_ + m];
      }
      while (s < Tc) {
        const int s2 = s + 15;
        unsigned int dsc_n = 0;
        float4 mc_n = make_float4(0.f, 0.f, 0.f, 0.f), mo_n = mc_n;
        float l0_n = 0.f;
        if (s2 < Tc) {
          dsc_n = descL[s2];
          const int mn = dsc_n & 2047;
          mo_n = mem04[(size_t)mn * 64 + lane];
          const bool fromM0n = (dsc_n & (1u << 12)) && (dsc_n & (1u << 11));
          mc_n = fromM0n ? mo_n : mcur4c[(size_t)(b * NSLOT + s2) * 64 + lane];
          l0_n = L0[(size_t)n * M_ + mn];
        }
        const int m = dsc_c & 2047;
        if (dsc_c & (1u << 12)) {  // pending update: apply, writeback
          mc_c.x = fmaf(g4.x, xpv.x - mc_c.x, mc_c.x);
          mc_c.y = fmaf(g4.y, xpv.y - mc_c.y, mc_c.y);
          mc_c.z = fmaf(g4.z, xpv.z - mc_c.z, mc_c.z);
          mc_c.w = fmaf(g4.w, xpv.w - mc_c.w, mc_c.w);
          mcur4[(size_t)(b * NSLOT + s) * 64 + lane] = mc_c;
          if (lane == 0) descL[s] = (unsigned int)m;
        }
        float p = mc_c.x * qv.x;
        p = fmaf(mc_c.y, qv.y, p);
        p = fmaf(mc_c.z, qv.z, p);
        p = fmaf(mc_c.w, qv.w, p);
#pragma unroll
        for (int off = 1; off < 64; off <<= 1) p += __shfl_xor(p, off, 64);
        const float cur = (p + qb) * 0.0625f;
        const float ce = expf(cur - c0);
        const float e0 = expf(l0_c - c0);
        acc.x = fmaf(ce, mc_c.x, fmaf(-e0, mo_c.x, acc.x));
        acc.y = fmaf(ce, mc_c.y, fmaf(-e0, mo_c.y, acc.y));
        acc.z = fmaf(ce, mc_c.z, fmaf(-e0, mo_c.z, acc.z));
        acc.w = fmaf(ce, mc_c.w, fmaf(-e0, mo_c.w, acc.w));
        if (lane == 0) {
          curE[s] = ce;
          e0sA[s] = e0;
          diffA[s] = ce - e0;
          candV[s] = cur;
          candI[s] = m;
        }
        dsc_c = dsc_n;
        mc_c = mc_n;
        mo_c = mo_n;
        l0_c = l0_n;
        s = s2;
      }
      ((float4*)dpart[wvid])[lane] = acc;
    } else {
      // wave 15: candidate prep + per-step prefetches
#pragma unroll
      for (int jj = 0; jj < 4; ++jj) {
        const int j = lane + jj * 64;
        const int ii = topi[n * TOPC + j];
        const bool fresh = (tpos[ii] < 0);
        candV[NSLOT + j] = fresh ? topv[n * TOPC + j] : -INFINITY;
        candI[NSLOT + j] = fresh ? ii : 0x7FFFFFFF;
      }
      const float4 c0v = ctxp4[(size_t)(0 * N_ + n) * 64 + lane];
      const float4 c1v = ctxp4[(size_t)(1 * N_ + n) * 64 + lane];
      const float4 c2v = ctxp4[(size_t)(2 * N_ + n) * 64 + lane];
      const float4 c3v = ctxp4[(size_t)(3 * N_ + n) * 64 + lane];
      ((float4*)CTX0_s)[lane] = make_float4(c0v.x + c1v.x + c2v.x + c3v.x,
                                            c0v.y + c1v.y + c2v.y + c3v.y,
                                            c0v.z + c1v.z + c2v.z + c3v.z,
                                            c0v.w + c1v.w + c2v.w + c3v.w);
      ((float4*)xgp_s)[lane] = xgp4[(size_t)n * 64 + lane];
      if (t + 1 < S_) {
        ((float4*)qt_s[par ^ 1])[lane] = qt4[(size_t)(n + B_) * 64 + lane];
        ((float4*)xt_s[par ^ 1])[lane] = x4[(size_t)(b * S_ + t + 1) * 64 + lane];
      }
    }
    __syncthreads();  // B1

    // ===== PB: GEMV (waves 0-14) || denom + selection (wave 15)
    if (wvid < 15) {
      const int kbase = 17 * wvid;
      const int nr = (wvid == 14) ? 18 : 17;
      float mynum = 0.f;
      if (lane < nr) {
        const int k = (lane == 17) ? 255 : (kbase + lane);
        float nv = CTX0_s[k];
#pragma unroll
        for (int p = 0; p < 15; ++p) nv += dpart[p][k];
        mynum = nv;
      }
      float4 a1 = make_float4(0.f, 0.f, 0.f, 0.f);
      float4 a2 = make_float4(0.f, 0.f, 0.f, 0.f);
#pragma unroll
      for (int j = 0; j < 17; ++j) {
        const float nv = __int_as_float(__builtin_amdgcn_readlane(__float_as_int(mynum), j));
        a1.x = fmaf(nv, wreg[j].x, a1.x); a1.y = fmaf(nv, wreg[j].y, a1.y);
        a1.z = fmaf(nv, wreg[j].z, a1.z); a1.w = fmaf(nv, wreg[j].w, a1.w);
        const int r = kbase + j;
        const float4 w4 = (r >= CACHE0) ? wvlds4[(size_t)(r - CACHE0) * 64 + lane]
                                        : Wg4[(size_t)r * 64 + lane];
        a2.x = fmaf(nv, w4.x, a2.x); a2.y = fmaf(nv, w4.y, a2.y);
        a2.z = fmaf(nv, w4.z, a2.z); a2.w = fmaf(nv, w4.w, a2.w);
      }
      if (wvid == 14) {
        const float nv = __int_as_float(__builtin_amdgcn_readlane(__float_as_int(mynum), 17));
        a1.x = fmaf(nv, wreg[17].x, a1.x); a1.y = fmaf(nv, wreg[17].y, a1.y);
        a1.z = fmaf(nv, wreg[17].z, a1.z); a1.w = fmaf(nv, wreg[17].w, a1.w);
        const float4 w4 = wvlds4[(size_t)(255 - CACHE0) * 64 + lane];
        a2.x = fmaf(nv, w4.x, a2.x); a2.y = fmaf(nv, w4.y, a2.y);
        a2.z = fmaf(nv, w4.z, a2.z); a2.w = fmaf(nv, w4.w, a2.w);
      }
      ((float4*)fpart[wvid])[lane] = a1;
      ((float4*)fpart2[wvid])[lane] = a2;
    } else {
      double ds = 0.0;
      for (int s = lane; s < Tc; s += 64) ds += (double)diffA[s];
      for (int off = 32; off > 0; off >>= 1) ds += __shfl_down(ds, off, 64);
      if (lane == 0) inv_esum = (float)(1.0 / (sum0s[t] + ds));
      if (t + 1 < S_) {
        float cv[8];
        int ci[8];
#pragma unroll
        for (int j = 0; j < 8; ++j) {
          cv[j] = candV[lane * 8 + j];
          ci[j] = candI[lane * 8 + j];
        }
        for (int r = 0; r < TK; ++r) {
          float bvv = cv[0];
          int bii = ci[0];
#pragma unroll
          for (int j = 1; j < 8; ++j)
            if (cv[j] > bvv || (cv[j] == bvv && ci[j] < bii)) { bvv = cv[j]; bii = ci[j]; }
#pragma unroll
          for (int off = 1; off < 64; off <<= 1) {
            float ov = __shfl_xor(bvv, off, 64);
            int oi = __shfl_xor(bii, off, 64);
            if (ov > bvv || (ov == bvv && oi < bii)) { bvv = ov; bii = oi; }
          }
          if (lane == 0) selIdx[r] = bii;
#pragma unroll
          for (int j = 0; j < 8; ++j)
            if (ci[j] == bii) { cv[j] = -INFINITY; ci[j] = 0x7FFFFFFF; }
        }
        if (lane == 0) {
          int tc = Tcount;
          for (int k = 0; k < TK; ++k) {
            const int m = selIdx[k];
            int s = tpos[m];
            unsigned int fresh = 0;
            if (s < 0) {
              s = tc++;
              tpos[m] = (short)s;
              candI[s] = m;
              fresh = 1;
            }
            descL[s] = (unsigned int)m | (fresh << 11) | (1u << 12);
          }
          Tcount = tc;
        }
      }
    }
    __syncthreads();  // B2

    // ===== PC: finalize out & gate =====
    if (tid < D_) {
      float o = 0.f;
#pragma unroll
      for (int p = 0; p < 15; ++p) o += fpart[p][tid];
      o = o * inv_esum + bv_s[tid];
      out[((size_t)b * S_ + t) * D_ + tid] = o;
    } else if (tid < 2 * D_) {
      const int d = tid - D_;
      float gg = 0.f;
#pragma unroll
      for (int p = 0; p < 15; ++p) gg += fpart2[p][d];
      const float gin = xgp_s[d] + gg * inv_esum + bvg_s[d];
      g_s[d] = 1.0f / (1.0f + expf(-gin));
    }
    __syncthreads();  // B3
  }
}

// ---------------------------------------------------------------------------
extern "C" void kernel_launch(void* const* d_in, const int* in_sizes, int n_in,
                              void* d_out, int out_size, void* d_ws, size_t ws_size,
                              hipStream_t stream) {
  const float* x = (const float*)d_in[0];
  const float* mem0 = (const float*)d_in[1];
  const float* Wq = (const float*)d_in[2];
  const float* bq = (const float*)d_in[3];
  const float* Wk = (const float*)d_in[4];
  const float* bk = (const float*)d_in[5];
  const float* Wv = (const float*)d_in[6];
  const float* bv = (const float*)d_in[7];
  const float* Wg = (const float*)d_in[8];
  const float* bg = (const float*)d_in[9];
  float* out = (float*)d_out;
  float* ws = (float*)d_ws;

  size_t o = 0;
  float* WkT = ws + o;    o += (size_t)D_ * D_;
  float* qt = ws + o;     o += (size_t)N_ * D_;
  float* qbk = ws + o;    o += N_;
  float* xgp = ws + o;    o += (size_t)N_ * D_;
  float* L0 = ws + o;     o += (size_t)N_ * M_;
  float* M0 = ws + o;     o += N_;
  double* SumE0 = (double*)(ws + o); o += 2 * N_;
  float* ctxp = ws + o;   o += (size_t)KSPLIT * N_ * D_;
  float* topv = ws + o;   o += (size_t)N_ * TOPC;
  int* topi = (int*)(ws + o); o += (size_t)N_ * TOPC;
  float* WvWgB = ws + o;  o += (size_t)D_ * D_;
  float* bvg = ws + o;    o += D_;
  float* memcur = ws + o; o += (size_t)B_ * NSLOT * D_;

  k_wvwgT<<<dim3(81), dim3(256), 0, stream>>>(Wv, Wg, bv, bg, Wk, WvWgB, bvg, WkT);
  k_qproj<<<dim3(N_), dim3(256), 0, stream>>>(x, Wq, bq, bk, WkT, Wg, qt, qbk, xgp);
  k_L0<<<dim3(M_ / 64, N_ / 64), dim3(256), 0, stream>>>(qt, mem0, qbk, L0);
  k_sortstats<<<dim3(N_), dim3(1024), 0, stream>>>(L0, topv, topi, M0, SumE0);
  k_ctxpart<<<dim3(KSPLIT, N_ / 32, D_ / 64), dim3(256), 0, stream>>>(L0, M0, mem0, ctxp);
  k_scan<<<dim3(B_), dim3(1024), 0, stream>>>(x, mem0, Wv, bv, WvWgB, bvg, qt, qbk, xgp,
                                              L0, M0, SumE0, ctxp, topv, topi, memcur, out);
}